// Round 1
// baseline (3354.034 us; speedup 1.0000x reference)
//
#include <hip/hip_runtime.h>

// SSGC: h = alpha*x0 + (1-alpha)/K * sum_{k=1..K} (D^-1/2 A_hat D^-1/2)^k x0 ; out = h W^T + b
// N=50000 nodes, E=1.6M edges, D=128, K=16, alpha=0.05.
// Strategy: build dst-sorted CSR once per launch (no float atomics), then 16
// gather-style SpMM hops (1 block / node, 1 thread / feature), GEMM epilogue in-place in d_out.

#define N_NODES 50000
#define N_EDGES 1600000
#define D 128
#define K_HOPS 16
#define ALPHA 0.05f

__global__ void deg_kernel(const int* __restrict__ dst, int* __restrict__ deg, int e) {
    int i = blockIdx.x * blockDim.x + threadIdx.x;
    if (i < e) atomicAdd(&deg[dst[i]], 1);
}

__global__ void dinv_kernel(const int* __restrict__ deg, float* __restrict__ dinv, int n) {
    int i = blockIdx.x * blockDim.x + threadIdx.x;
    if (i < n) dinv[i] = rsqrtf((float)(deg[i] + 1));  // +1 = self loop
}

// Exclusive scan of deg -> row_start (single block, chunked Hillis-Steele).
__global__ void scan_kernel(const int* __restrict__ deg, int* __restrict__ row_start, int n) {
    __shared__ int smem[1024];
    __shared__ int carry_s;
    if (threadIdx.x == 0) carry_s = 0;
    __syncthreads();
    for (int base = 0; base < n; base += 1024) {
        int i = base + (int)threadIdx.x;
        int v = (i < n) ? deg[i] : 0;
        smem[threadIdx.x] = v;
        __syncthreads();
        for (int off = 1; off < 1024; off <<= 1) {
            int t = (threadIdx.x >= (unsigned)off) ? smem[threadIdx.x - off] : 0;
            __syncthreads();
            smem[threadIdx.x] += t;
            __syncthreads();
        }
        if (i < n) row_start[i] = carry_s + smem[threadIdx.x] - v;  // exclusive
        int total = smem[1023];
        __syncthreads();
        if (threadIdx.x == 0) carry_s += total;
        __syncthreads();
    }
    if (threadIdx.x == 0) row_start[n] = carry_s;
}

__global__ void scatter_kernel(const int* __restrict__ src, const int* __restrict__ dst,
                               const int* __restrict__ row_start, int* __restrict__ cursor,
                               int* __restrict__ csr_src, int e) {
    int i = blockIdx.x * blockDim.x + threadIdx.x;
    if (i < e) {
        int d = dst[i];
        int pos = atomicAdd(&cursor[d], 1);
        csr_src[row_start[d] + pos] = src[i];
    }
}

__global__ void init_kernel(const float* __restrict__ x0, float* __restrict__ x,
                            float* __restrict__ h, int n) {
    int i = blockIdx.x * blockDim.x + threadIdx.x;
    if (i < n) {
        float v = x0[i];
        x[i] = v;
        h[i] = ALPHA * v;
    }
}

// One block (128 threads) per node; thread t owns feature t.
__global__ void agg_kernel(const float* __restrict__ x, float* __restrict__ y,
                           float* __restrict__ h, const float* __restrict__ dinv,
                           const int* __restrict__ row_start, const int* __restrict__ csr_src) {
    int node = blockIdx.x;
    int t = threadIdx.x;
    float di = dinv[node];
    float acc = di * di * x[(size_t)node * D + t];  // self loop
    int r0 = row_start[node], r1 = row_start[node + 1];
    for (int e = r0; e < r1; ++e) {
        int s = csr_src[e];
        acc += di * dinv[s] * x[(size_t)s * D + t];
    }
    y[(size_t)node * D + t] = acc;
    h[(size_t)node * D + t] += ((1.0f - ALPHA) / K_HOPS) * acc;
}

// out[n,t] = sum_j h[n,j] * W[t,j] + bias[t]; in-place safe (row staged in LDS).
__global__ void gemm_kernel(const float* __restrict__ h, const float* __restrict__ w,
                            const float* __restrict__ bias, float* __restrict__ out) {
    __shared__ float row[D];
    int node = blockIdx.x;
    int t = threadIdx.x;
    row[t] = h[(size_t)node * D + t];
    __syncthreads();
    float acc = bias[t];
    const float* wr = w + (size_t)t * D;
#pragma unroll 8
    for (int j = 0; j < D; ++j) acc += row[j] * wr[j];
    out[(size_t)node * D + t] = acc;
}

extern "C" void kernel_launch(void* const* d_in, const int* in_sizes, int n_in,
                              void* d_out, int out_size, void* d_ws, size_t ws_size,
                              hipStream_t stream) {
    const float* node_emb = (const float*)d_in[0];
    const int*   edge     = (const int*)d_in[1];   // [2, E] flattened: row 0 = src, row 1 = dst
    const float* weight   = (const float*)d_in[2]; // [D_OUT, D_IN] row-major
    const float* bias     = (const float*)d_in[3];
    float* out = (float*)d_out;                    // holds h during hops, then final output

    char* ws = (char*)d_ws;
    float* x        = (float*)ws; ws += (size_t)N_NODES * D * sizeof(float);
    float* y        = (float*)ws; ws += (size_t)N_NODES * D * sizeof(float);
    int*   csr_src  = (int*)ws;   ws += (size_t)N_EDGES * sizeof(int);
    int*   deg      = (int*)ws;   ws += (size_t)N_NODES * sizeof(int);
    int*   row_start= (int*)ws;   ws += (size_t)(N_NODES + 1) * sizeof(int);
    int*   cursor   = (int*)ws;   ws += (size_t)N_NODES * sizeof(int);
    float* dinv     = (float*)ws; ws += (size_t)N_NODES * sizeof(float);

    const int* src = edge;
    const int* dst = edge + N_EDGES;

    hipMemsetAsync(deg, 0, N_NODES * sizeof(int), stream);
    hipMemsetAsync(cursor, 0, N_NODES * sizeof(int), stream);

    deg_kernel<<<(N_EDGES + 255) / 256, 256, 0, stream>>>(dst, deg, N_EDGES);
    dinv_kernel<<<(N_NODES + 255) / 256, 256, 0, stream>>>(deg, dinv, N_NODES);
    scan_kernel<<<1, 1024, 0, stream>>>(deg, row_start, N_NODES);
    scatter_kernel<<<(N_EDGES + 255) / 256, 256, 0, stream>>>(src, dst, row_start, cursor,
                                                              csr_src, N_EDGES);
    init_kernel<<<(N_NODES * D + 255) / 256, 256, 0, stream>>>(node_emb, x, out, N_NODES * D);

    for (int k = 0; k < K_HOPS; ++k) {
        agg_kernel<<<N_NODES, D, 0, stream>>>(x, y, out, dinv, row_start, csr_src);
        float* tmp = x; x = y; y = tmp;
    }

    gemm_kernel<<<N_NODES, D, 0, stream>>>(out, weight, bias, out);
}

// Round 3
// 2184.233 us; speedup vs baseline: 1.5356x; 1.5356x over previous
//
#include <hip/hip_runtime.h>

// SSGC: h = alpha*x0 + (1-alpha)/K * sum_{k=1..K} (D^-1/2 A_hat D^-1/2)^k x0 ; out = h W^T + b
// N=50000, E=1.6M, D=128, K=16, alpha=0.05.
// R3: same as R2 (wave-per-node gather SpMM, x4 unrolled, precomputed edge norms,
//     64x64 register-tiled GEMM) but race-free buffer plan:
//       h lives in workspace (hbuf); hop state ping-pongs d_out <-> xalt;
//       GEMM reads hbuf, writes d_out (out-of-place, no block race).

#define N_NODES 50000
#define N_EDGES 1600000
#define D 128
#define K_HOPS 16
#define ALPHA 0.05f
#define HCOEF ((1.0f - ALPHA) / (float)K_HOPS)

__global__ void deg_kernel(const int* __restrict__ dst, int* __restrict__ deg, int e) {
    int i = blockIdx.x * blockDim.x + threadIdx.x;
    if (i < e) atomicAdd(&deg[dst[i]], 1);
}

// dinv = 1/sqrt(deg+1); selfw = dinv^2 (self-loop weight)
__global__ void dinv_kernel(const int* __restrict__ deg, float* __restrict__ dinv,
                            float* __restrict__ selfw, int n) {
    int i = blockIdx.x * blockDim.x + threadIdx.x;
    if (i < n) {
        float di = rsqrtf((float)(deg[i] + 1));
        dinv[i] = di;
        selfw[i] = di * di;
    }
}

// Exclusive scan of deg -> row_start. Single block, 1024 threads, shfl wave scans.
__global__ void scan_kernel(const int* __restrict__ deg, int* __restrict__ row_start, int n) {
    __shared__ int wsum[16];
    __shared__ int tot_s;
    __shared__ int carry_s;
    int tid = threadIdx.x, lane = tid & 63, wid = tid >> 6;
    if (tid == 0) carry_s = 0;
    __syncthreads();
    for (int base = 0; base < n; base += 1024) {
        int i = base + tid;
        int v = (i < n) ? deg[i] : 0;
        int s = v;
        #pragma unroll
        for (int off = 1; off < 64; off <<= 1) {
            int t = __shfl_up(s, off, 64);
            if (lane >= off) s += t;
        }
        if (lane == 63) wsum[wid] = s;
        __syncthreads();                       // (A) wsum ready
        if (tid == 0) {
            int run = 0;
            #pragma unroll
            for (int w = 0; w < 16; ++w) { int t = wsum[w]; wsum[w] = run; run += t; }
            tot_s = run;
        }
        __syncthreads();                       // (B) offsets ready, carry stable
        if (i < n) row_start[i] = carry_s + wsum[wid] + (s - v);
        __syncthreads();                       // (C) all reads of carry_s done
        if (tid == 0) carry_s += tot_s;
    }
    __syncthreads();
    if (tid == 0) row_start[n] = carry_s;
}

// Scatter edges into dst-sorted CSR; also precompute per-edge norm weight.
__global__ void scatter_kernel(const int* __restrict__ src, const int* __restrict__ dst,
                               const int* __restrict__ row_start, int* __restrict__ cursor,
                               int* __restrict__ csr_src, float* __restrict__ csr_w,
                               const float* __restrict__ dinv, int e) {
    int i = blockIdx.x * blockDim.x + threadIdx.x;
    if (i < e) {
        int d = dst[i];
        int s = src[i];
        int pos = row_start[d] + atomicAdd(&cursor[d], 1);
        csr_src[pos] = s;
        csr_w[pos] = dinv[d] * dinv[s];
    }
}

__global__ void init_kernel(const float2* __restrict__ x0, float2* __restrict__ x,
                            float2* __restrict__ h, int n2) {
    int i = blockIdx.x * blockDim.x + threadIdx.x;
    if (i < n2) {
        float2 v = x0[i];
        x[i] = v;
        h[i] = make_float2(ALPHA * v.x, ALPHA * v.y);
    }
}

// One wave (64 lanes) per node; lane owns features [2*lane, 2*lane+1].
// 4 waves (4 nodes) per 256-thread block. Neighbor loop unrolled x4 for MLP.
__global__ __launch_bounds__(256) void agg_kernel(
    const float2* __restrict__ x2, float2* __restrict__ y2, float2* __restrict__ h2,
    const float* __restrict__ selfw, const int* __restrict__ row_start,
    const int* __restrict__ csr_src, const float* __restrict__ csr_w) {
    int wid = threadIdx.x >> 6;
    int lane = threadIdx.x & 63;
    int node = blockIdx.x * 4 + wid;
    if (node >= N_NODES) return;

    int r0 = row_start[node];
    int r1 = row_start[node + 1];
    size_t o = (size_t)node * 64 + lane;

    float2 v0s = x2[o];
    float sw = selfw[node];
    float accx = sw * v0s.x, accy = sw * v0s.y;

    int e = r0;
    for (; e + 4 <= r1; e += 4) {
        int s0 = csr_src[e + 0], s1 = csr_src[e + 1];
        int s2 = csr_src[e + 2], s3 = csr_src[e + 3];
        float w0 = csr_w[e + 0], w1 = csr_w[e + 1];
        float w2 = csr_w[e + 2], w3 = csr_w[e + 3];
        float2 a = x2[(size_t)s0 * 64 + lane];
        float2 b = x2[(size_t)s1 * 64 + lane];
        float2 c = x2[(size_t)s2 * 64 + lane];
        float2 d = x2[(size_t)s3 * 64 + lane];
        accx += w0 * a.x + w1 * b.x + w2 * c.x + w3 * d.x;
        accy += w0 * a.y + w1 * b.y + w2 * c.y + w3 * d.y;
    }
    for (; e < r1; ++e) {
        int s = csr_src[e];
        float w = csr_w[e];
        float2 a = x2[(size_t)s * 64 + lane];
        accx += w * a.x;
        accy += w * a.y;
    }

    y2[o] = make_float2(accx, accy);
    float2 hv = h2[o];
    hv.x += HCOEF * accx;
    hv.y += HCOEF * accy;
    h2[o] = hv;
}

// out[r][c] = sum_k h[r][k]*W[c][k] + bias[c]. h and out are DIFFERENT buffers.
// Block: 64 rows x 64 cols, 256 threads, 4x4 acc/thread.
// LDS: A and B tiles stored k-major (transposed), 32 KB each.
__global__ __launch_bounds__(256) void gemm_kernel(
    const float* __restrict__ h, const float* __restrict__ w,
    const float* __restrict__ bias, float* __restrict__ out) {
    __shared__ float sAT[128][64];   // [k][row]
    __shared__ float sBT[128][64];   // [k][col]
    int tid = threadIdx.x;
    int row0 = blockIdx.x * 64;
    int col0 = blockIdx.y * 64;

    // Stage A: h[row0+r][4kq..+4] -> sAT[4kq+j][r]. r spans lanes -> conflict-free LDS writes.
    for (int idx = tid; idx < 64 * 32; idx += 256) {
        int r = idx & 63, kq = idx >> 6;
        float4 v;
        if (row0 + r < N_NODES)
            v = *(const float4*)&h[(size_t)(row0 + r) * D + kq * 4];
        else
            v = make_float4(0.f, 0.f, 0.f, 0.f);
        sAT[kq * 4 + 0][r] = v.x;
        sAT[kq * 4 + 1][r] = v.y;
        sAT[kq * 4 + 2][r] = v.z;
        sAT[kq * 4 + 3][r] = v.w;
    }
    // Stage B: w[col0+c][4kq..+4] -> sBT[4kq+j][c].
    for (int idx = tid; idx < 64 * 32; idx += 256) {
        int c = idx & 63, kq = idx >> 6;
        float4 v = *(const float4*)&w[(size_t)(col0 + c) * D + kq * 4];
        sBT[kq * 4 + 0][c] = v.x;
        sBT[kq * 4 + 1][c] = v.y;
        sBT[kq * 4 + 2][c] = v.z;
        sBT[kq * 4 + 3][c] = v.w;
    }
    __syncthreads();

    int cg = tid & 15;    // cols cg*4..+4
    int rg = tid >> 4;    // rows rg*4..+4
    float acc[4][4] = {};
    #pragma unroll 2
    for (int k = 0; k < 128; ++k) {
        float4 a = *(const float4*)&sAT[k][rg * 4];
        float4 b = *(const float4*)&sBT[k][cg * 4];
        acc[0][0] += a.x * b.x; acc[0][1] += a.x * b.y; acc[0][2] += a.x * b.z; acc[0][3] += a.x * b.w;
        acc[1][0] += a.y * b.x; acc[1][1] += a.y * b.y; acc[1][2] += a.y * b.z; acc[1][3] += a.y * b.w;
        acc[2][0] += a.z * b.x; acc[2][1] += a.z * b.y; acc[2][2] += a.z * b.z; acc[2][3] += a.z * b.w;
        acc[3][0] += a.w * b.x; acc[3][1] += a.w * b.y; acc[3][2] += a.w * b.z; acc[3][3] += a.w * b.w;
    }

    float4 bv = *(const float4*)&bias[col0 + cg * 4];
    #pragma unroll
    for (int i = 0; i < 4; ++i) {
        int r = row0 + rg * 4 + i;
        if (r < N_NODES) {
            float4 ov = make_float4(acc[i][0] + bv.x, acc[i][1] + bv.y,
                                    acc[i][2] + bv.z, acc[i][3] + bv.w);
            *(float4*)&out[(size_t)r * D + col0 + cg * 4] = ov;
        }
    }
}

extern "C" void kernel_launch(void* const* d_in, const int* in_sizes, int n_in,
                              void* d_out, int out_size, void* d_ws, size_t ws_size,
                              hipStream_t stream) {
    const float* node_emb = (const float*)d_in[0];
    const int*   edge     = (const int*)d_in[1];   // [2,E]: row 0 = src, row 1 = dst
    const float* weight   = (const float*)d_in[2]; // [D_OUT, D_IN] row-major
    const float* bias     = (const float*)d_in[3];
    float* out = (float*)d_out;

    char* ws = (char*)d_ws;
    float* hbuf     = (float*)ws; ws += (size_t)N_NODES * D * sizeof(float);  // persistent h
    float* xalt     = (float*)ws; ws += (size_t)N_NODES * D * sizeof(float);  // ping-pong partner
    int*   csr_src  = (int*)ws;   ws += (size_t)N_EDGES * sizeof(int);
    float* csr_w    = (float*)ws; ws += (size_t)N_EDGES * sizeof(float);
    int*   deg      = (int*)ws;   ws += (size_t)N_NODES * sizeof(int);
    int*   row_start= (int*)ws;   ws += (size_t)(N_NODES + 1) * sizeof(int);
    int*   cursor   = (int*)ws;   ws += (size_t)N_NODES * sizeof(int);
    float* dinv     = (float*)ws; ws += (size_t)N_NODES * sizeof(float);
    float* selfw    = (float*)ws; ws += (size_t)N_NODES * sizeof(float);

    const int* srcp = edge;
    const int* dstp = edge + N_EDGES;

    hipMemsetAsync(deg, 0, N_NODES * sizeof(int), stream);
    hipMemsetAsync(cursor, 0, N_NODES * sizeof(int), stream);

    deg_kernel<<<(N_EDGES + 255) / 256, 256, 0, stream>>>(dstp, deg, N_EDGES);
    dinv_kernel<<<(N_NODES + 255) / 256, 256, 0, stream>>>(deg, dinv, selfw, N_NODES);
    scan_kernel<<<1, 1024, 0, stream>>>(deg, row_start, N_NODES);
    scatter_kernel<<<(N_EDGES + 255) / 256, 256, 0, stream>>>(srcp, dstp, row_start, cursor,
                                                              csr_src, csr_w, dinv, N_EDGES);

    // x starts in d_out; h accumulates in hbuf. Ping-pong d_out <-> xalt.
    int n2 = N_NODES * D / 2;
    init_kernel<<<(n2 + 255) / 256, 256, 0, stream>>>((const float2*)node_emb, (float2*)out,
                                                      (float2*)hbuf, n2);

    float* cur = out;
    float* nxt = xalt;
    for (int k = 0; k < K_HOPS; ++k) {
        agg_kernel<<<(N_NODES + 3) / 4, 256, 0, stream>>>((const float2*)cur, (float2*)nxt,
                                                          (float2*)hbuf, selfw, row_start,
                                                          csr_src, csr_w);
        float* tmp = cur; cur = nxt; nxt = tmp;
    }

    // Out-of-place GEMM: reads hbuf, writes d_out (stale x in d_out is dead).
    dim3 ggrid((N_NODES + 63) / 64, 2);
    gemm_kernel<<<ggrid, 256, 0, stream>>>(hbuf, weight, bias, out);
}

// Round 4
// 2050.628 us; speedup vs baseline: 1.6356x; 1.0652x over previous
//
#include <hip/hip_runtime.h>

// SSGC: h = alpha*x0 + (1-alpha)/K * sum_{k=1..K} (D^-1/2 A_hat D^-1/2)^k x0 ; out = h W^T + b
// N=50000, E=1.6M, D=128, K=16, alpha=0.05.
// R4: packed 8B edge records (src,w) -> one coalesced record load per wave + shfl broadcast
//     (kills 2/3 of agg vmem instrs), x8-unrolled row gathers; scatter writes one 8B store
//     per edge with rank precomputed in deg pass (no cursor atomic).

#define N_NODES 50000
#define N_EDGES 1600000
#define D 128
#define K_HOPS 16
#define ALPHA 0.05f
#define HCOEF ((1.0f - ALPHA) / (float)K_HOPS)

// Count in-degree and assign each edge its within-destination rank (coalesced write).
__global__ void deg_kernel(const int* __restrict__ dst, int* __restrict__ deg,
                           int* __restrict__ rank, int e) {
    int i = blockIdx.x * blockDim.x + threadIdx.x;
    if (i < e) rank[i] = atomicAdd(&deg[dst[i]], 1);
}

// dinv = 1/sqrt(deg+1); selfw = dinv^2 (self-loop weight)
__global__ void dinv_kernel(const int* __restrict__ deg, float* __restrict__ dinv,
                            float* __restrict__ selfw, int n) {
    int i = blockIdx.x * blockDim.x + threadIdx.x;
    if (i < n) {
        float di = rsqrtf((float)(deg[i] + 1));
        dinv[i] = di;
        selfw[i] = di * di;
    }
}

// Exclusive scan of deg -> row_start. Single block, 1024 threads, shfl wave scans.
__global__ void scan_kernel(const int* __restrict__ deg, int* __restrict__ row_start, int n) {
    __shared__ int wsum[16];
    __shared__ int tot_s;
    __shared__ int carry_s;
    int tid = threadIdx.x, lane = tid & 63, wid = tid >> 6;
    if (tid == 0) carry_s = 0;
    __syncthreads();
    for (int base = 0; base < n; base += 1024) {
        int i = base + tid;
        int v = (i < n) ? deg[i] : 0;
        int s = v;
        #pragma unroll
        for (int off = 1; off < 64; off <<= 1) {
            int t = __shfl_up(s, off, 64);
            if (lane >= off) s += t;
        }
        if (lane == 63) wsum[wid] = s;
        __syncthreads();                       // (A) wsum ready
        if (tid == 0) {
            int run = 0;
            #pragma unroll
            for (int w = 0; w < 16; ++w) { int t = wsum[w]; wsum[w] = run; run += t; }
            tot_s = run;
        }
        __syncthreads();                       // (B) offsets ready, carry stable
        if (i < n) row_start[i] = carry_s + wsum[wid] + (s - v);
        __syncthreads();                       // (C) all reads of carry_s done
        if (tid == 0) carry_s += tot_s;
    }
    __syncthreads();
    if (tid == 0) row_start[n] = carry_s;
}

// One 8B scattered store per edge: record = (src, bitcast(norm weight)).
__global__ void scatter_kernel(const int* __restrict__ src, const int* __restrict__ dst,
                               const int* __restrict__ rank,
                               const int* __restrict__ row_start, int2* __restrict__ csr,
                               const float* __restrict__ dinv, int e) {
    int i = blockIdx.x * blockDim.x + threadIdx.x;
    if (i < e) {
        int d = dst[i];
        int s = src[i];
        int pos = row_start[d] + rank[i];
        csr[pos] = make_int2(s, __float_as_int(dinv[d] * dinv[s]));
    }
}

__global__ void init_kernel(const float2* __restrict__ x0, float2* __restrict__ x,
                            float2* __restrict__ h, int n2) {
    int i = blockIdx.x * blockDim.x + threadIdx.x;
    if (i < n2) {
        float2 v = x0[i];
        x[i] = v;
        h[i] = make_float2(ALPHA * v.x, ALPHA * v.y);
    }
}

// One wave (64 lanes) per node; lane owns features [2*lane, 2*lane+1].
// Edge records loaded 64-at-a-time coalesced, broadcast with shfl; gathers unrolled x8.
__global__ __launch_bounds__(256) void agg_kernel(
    const float2* __restrict__ x2, float2* __restrict__ y2, float2* __restrict__ h2,
    const float* __restrict__ selfw, const int* __restrict__ row_start,
    const int2* __restrict__ csr) {
    int wid = threadIdx.x >> 6;
    int lane = threadIdx.x & 63;
    int node = blockIdx.x * 4 + wid;
    if (node >= N_NODES) return;

    int r0 = row_start[node];
    int r1 = row_start[node + 1];
    int deg = r1 - r0;
    size_t o = (size_t)node * 64 + lane;

    float2 vs = x2[o];
    float sw = selfw[node];
    float accx = sw * vs.x, accy = sw * vs.y;

    for (int base = 0; base < deg; base += 64) {
        int cnt = deg - base;
        if (cnt > 64) cnt = 64;
        int idx = r0 + base + lane;
        if (idx >= r1) idx = r1 - 1;           // clamped lanes are never shfl-read
        int2 rec = csr[idx];                   // one coalesced dwordx2 per wave

        int j = 0;
        for (; j + 8 <= cnt; j += 8) {
            int s0 = __shfl(rec.x, j + 0), s1 = __shfl(rec.x, j + 1);
            int s2 = __shfl(rec.x, j + 2), s3 = __shfl(rec.x, j + 3);
            int s4 = __shfl(rec.x, j + 4), s5 = __shfl(rec.x, j + 5);
            int s6 = __shfl(rec.x, j + 6), s7 = __shfl(rec.x, j + 7);
            float w0 = __int_as_float(__shfl(rec.y, j + 0));
            float w1 = __int_as_float(__shfl(rec.y, j + 1));
            float w2 = __int_as_float(__shfl(rec.y, j + 2));
            float w3 = __int_as_float(__shfl(rec.y, j + 3));
            float w4 = __int_as_float(__shfl(rec.y, j + 4));
            float w5 = __int_as_float(__shfl(rec.y, j + 5));
            float w6 = __int_as_float(__shfl(rec.y, j + 6));
            float w7 = __int_as_float(__shfl(rec.y, j + 7));
            float2 a0 = x2[(size_t)s0 * 64 + lane];
            float2 a1 = x2[(size_t)s1 * 64 + lane];
            float2 a2 = x2[(size_t)s2 * 64 + lane];
            float2 a3 = x2[(size_t)s3 * 64 + lane];
            float2 a4 = x2[(size_t)s4 * 64 + lane];
            float2 a5 = x2[(size_t)s5 * 64 + lane];
            float2 a6 = x2[(size_t)s6 * 64 + lane];
            float2 a7 = x2[(size_t)s7 * 64 + lane];
            accx += w0 * a0.x + w1 * a1.x + w2 * a2.x + w3 * a3.x;
            accy += w0 * a0.y + w1 * a1.y + w2 * a2.y + w3 * a3.y;
            accx += w4 * a4.x + w5 * a5.x + w6 * a6.x + w7 * a7.x;
            accy += w4 * a4.y + w5 * a5.y + w6 * a6.y + w7 * a7.y;
        }
        for (; j < cnt; ++j) {
            int s = __shfl(rec.x, j);
            float w = __int_as_float(__shfl(rec.y, j));
            float2 a = x2[(size_t)s * 64 + lane];
            accx += w * a.x;
            accy += w * a.y;
        }
    }

    y2[o] = make_float2(accx, accy);
    float2 hv = h2[o];
    hv.x += HCOEF * accx;
    hv.y += HCOEF * accy;
    h2[o] = hv;
}

// out[r][c] = sum_k h[r][k]*W[c][k] + bias[c]. h and out are DIFFERENT buffers.
// Block: 64 rows x 64 cols, 256 threads, 4x4 acc/thread. k-major LDS tiles.
__global__ __launch_bounds__(256) void gemm_kernel(
    const float* __restrict__ h, const float* __restrict__ w,
    const float* __restrict__ bias, float* __restrict__ out) {
    __shared__ float sAT[128][64];   // [k][row]
    __shared__ float sBT[128][64];   // [k][col]
    int tid = threadIdx.x;
    int row0 = blockIdx.x * 64;
    int col0 = blockIdx.y * 64;

    for (int idx = tid; idx < 64 * 32; idx += 256) {
        int r = idx & 63, kq = idx >> 6;
        float4 v;
        if (row0 + r < N_NODES)
            v = *(const float4*)&h[(size_t)(row0 + r) * D + kq * 4];
        else
            v = make_float4(0.f, 0.f, 0.f, 0.f);
        sAT[kq * 4 + 0][r] = v.x;
        sAT[kq * 4 + 1][r] = v.y;
        sAT[kq * 4 + 2][r] = v.z;
        sAT[kq * 4 + 3][r] = v.w;
    }
    for (int idx = tid; idx < 64 * 32; idx += 256) {
        int c = idx & 63, kq = idx >> 6;
        float4 v = *(const float4*)&w[(size_t)(col0 + c) * D + kq * 4];
        sBT[kq * 4 + 0][c] = v.x;
        sBT[kq * 4 + 1][c] = v.y;
        sBT[kq * 4 + 2][c] = v.z;
        sBT[kq * 4 + 3][c] = v.w;
    }
    __syncthreads();

    int cg = tid & 15;    // cols cg*4..+4
    int rg = tid >> 4;    // rows rg*4..+4
    float acc[4][4] = {};
    #pragma unroll 2
    for (int k = 0; k < 128; ++k) {
        float4 a = *(const float4*)&sAT[k][rg * 4];
        float4 b = *(const float4*)&sBT[k][cg * 4];
        acc[0][0] += a.x * b.x; acc[0][1] += a.x * b.y; acc[0][2] += a.x * b.z; acc[0][3] += a.x * b.w;
        acc[1][0] += a.y * b.x; acc[1][1] += a.y * b.y; acc[1][2] += a.y * b.z; acc[1][3] += a.y * b.w;
        acc[2][0] += a.z * b.x; acc[2][1] += a.z * b.y; acc[2][2] += a.z * b.z; acc[2][3] += a.z * b.w;
        acc[3][0] += a.w * b.x; acc[3][1] += a.w * b.y; acc[3][2] += a.w * b.z; acc[3][3] += a.w * b.w;
    }

    float4 bv = *(const float4*)&bias[col0 + cg * 4];
    #pragma unroll
    for (int i = 0; i < 4; ++i) {
        int r = row0 + rg * 4 + i;
        if (r < N_NODES) {
            float4 ov = make_float4(acc[i][0] + bv.x, acc[i][1] + bv.y,
                                    acc[i][2] + bv.z, acc[i][3] + bv.w);
            *(float4*)&out[(size_t)r * D + col0 + cg * 4] = ov;
        }
    }
}

extern "C" void kernel_launch(void* const* d_in, const int* in_sizes, int n_in,
                              void* d_out, int out_size, void* d_ws, size_t ws_size,
                              hipStream_t stream) {
    const float* node_emb = (const float*)d_in[0];
    const int*   edge     = (const int*)d_in[1];   // [2,E]: row 0 = src, row 1 = dst
    const float* weight   = (const float*)d_in[2]; // [D_OUT, D_IN] row-major
    const float* bias     = (const float*)d_in[3];
    float* out = (float*)d_out;

    char* ws = (char*)d_ws;
    float* hbuf     = (float*)ws; ws += (size_t)N_NODES * D * sizeof(float);  // persistent h
    float* xalt     = (float*)ws; ws += (size_t)N_NODES * D * sizeof(float);  // ping-pong partner
    int2*  csr      = (int2*)ws;  ws += (size_t)N_EDGES * sizeof(int2);
    int*   rank     = (int*)ws;   ws += (size_t)N_EDGES * sizeof(int);
    int*   deg      = (int*)ws;   ws += (size_t)N_NODES * sizeof(int);
    int*   row_start= (int*)ws;   ws += (size_t)(N_NODES + 1) * sizeof(int);
    float* dinv     = (float*)ws; ws += (size_t)N_NODES * sizeof(float);
    float* selfw    = (float*)ws; ws += (size_t)N_NODES * sizeof(float);

    const int* srcp = edge;
    const int* dstp = edge + N_EDGES;

    hipMemsetAsync(deg, 0, N_NODES * sizeof(int), stream);

    deg_kernel<<<(N_EDGES + 255) / 256, 256, 0, stream>>>(dstp, deg, rank, N_EDGES);
    dinv_kernel<<<(N_NODES + 255) / 256, 256, 0, stream>>>(deg, dinv, selfw, N_NODES);
    scan_kernel<<<1, 1024, 0, stream>>>(deg, row_start, N_NODES);
    scatter_kernel<<<(N_EDGES + 255) / 256, 256, 0, stream>>>(srcp, dstp, rank, row_start,
                                                              csr, dinv, N_EDGES);

    // x starts in d_out; h accumulates in hbuf. Ping-pong d_out <-> xalt.
    int n2 = N_NODES * D / 2;
    init_kernel<<<(n2 + 255) / 256, 256, 0, stream>>>((const float2*)node_emb, (float2*)out,
                                                      (float2*)hbuf, n2);

    float* cur = out;
    float* nxt = xalt;
    for (int k = 0; k < K_HOPS; ++k) {
        agg_kernel<<<(N_NODES + 3) / 4, 256, 0, stream>>>((const float2*)cur, (float2*)nxt,
                                                          (float2*)hbuf, selfw, row_start, csr);
        float* tmp = cur; cur = nxt; nxt = tmp;
    }

    // Out-of-place GEMM: reads hbuf, writes d_out (stale x in d_out is dead).
    dim3 ggrid((N_NODES + 63) / 64, 2);
    gemm_kernel<<<ggrid, 256, 0, stream>>>(hbuf, weight, bias, out);
}

// Round 5
// 1242.167 us; speedup vs baseline: 2.7001x; 1.6508x over previous
//
#include <hip/hip_runtime.h>

// SSGC: h = alpha*x0 + (1-alpha)/K * sum_{k=1..K} (D^-1/2 A_hat D^-1/2)^k x0 ; out = h W^T + b
// N=50000, E=1.6M, D=128, K=16, alpha=0.05.
// R5: bf16-packed feature rows (256B/row, halves random-gather traffic; h stays f32 and is
//     fed from the pre-rounding f32 accumulator), x16-unrolled gathers, packed 8B edge
//     records + shfl broadcast, rank-based scatter, 64x64 register-tiled f32 GEMM.

#define N_NODES 50000
#define N_EDGES 1600000
#define D 128
#define K_HOPS 16
#define ALPHA 0.05f
#define HCOEF ((1.0f - ALPHA) / (float)K_HOPS)

__device__ __forceinline__ unsigned int f2bf(float f) {
    unsigned int u = __float_as_uint(f);
    return (u + 0x7FFFu + ((u >> 16) & 1u)) >> 16;   // RNE
}
__device__ __forceinline__ unsigned int pack_bf2(float x, float y) {
    return f2bf(x) | (f2bf(y) << 16);
}
__device__ __forceinline__ float bf_lo(unsigned int w) { return __uint_as_float(w << 16); }
__device__ __forceinline__ float bf_hi(unsigned int w) { return __uint_as_float(w & 0xFFFF0000u); }

// Count in-degree and assign each edge its within-destination rank (coalesced write).
__global__ void deg_kernel(const int* __restrict__ dst, int* __restrict__ deg,
                           int* __restrict__ rank, int e) {
    int i = blockIdx.x * blockDim.x + threadIdx.x;
    if (i < e) rank[i] = atomicAdd(&deg[dst[i]], 1);
}

// dinv = 1/sqrt(deg+1); selfw = dinv^2 (self-loop weight)
__global__ void dinv_kernel(const int* __restrict__ deg, float* __restrict__ dinv,
                            float* __restrict__ selfw, int n) {
    int i = blockIdx.x * blockDim.x + threadIdx.x;
    if (i < n) {
        float di = rsqrtf((float)(deg[i] + 1));
        dinv[i] = di;
        selfw[i] = di * di;
    }
}

// Exclusive scan of deg -> row_start. Single block, 1024 threads, shfl wave scans.
__global__ void scan_kernel(const int* __restrict__ deg, int* __restrict__ row_start, int n) {
    __shared__ int wsum[16];
    __shared__ int tot_s;
    __shared__ int carry_s;
    int tid = threadIdx.x, lane = tid & 63, wid = tid >> 6;
    if (tid == 0) carry_s = 0;
    __syncthreads();
    for (int base = 0; base < n; base += 1024) {
        int i = base + tid;
        int v = (i < n) ? deg[i] : 0;
        int s = v;
        #pragma unroll
        for (int off = 1; off < 64; off <<= 1) {
            int t = __shfl_up(s, off, 64);
            if (lane >= off) s += t;
        }
        if (lane == 63) wsum[wid] = s;
        __syncthreads();                       // (A) wsum ready
        if (tid == 0) {
            int run = 0;
            #pragma unroll
            for (int w = 0; w < 16; ++w) { int t = wsum[w]; wsum[w] = run; run += t; }
            tot_s = run;
        }
        __syncthreads();                       // (B) offsets ready, carry stable
        if (i < n) row_start[i] = carry_s + wsum[wid] + (s - v);
        __syncthreads();                       // (C) all reads of carry_s done
        if (tid == 0) carry_s += tot_s;
    }
    __syncthreads();
    if (tid == 0) row_start[n] = carry_s;
}

// One 8B scattered store per edge: record = (src, bitcast(norm weight)).
__global__ void scatter_kernel(const int* __restrict__ src, const int* __restrict__ dst,
                               const int* __restrict__ rank,
                               const int* __restrict__ row_start, int2* __restrict__ csr,
                               const float* __restrict__ dinv, int e) {
    int i = blockIdx.x * blockDim.x + threadIdx.x;
    if (i < e) {
        int d = dst[i];
        int s = src[i];
        int pos = row_start[d] + rank[i];
        csr[pos] = make_int2(s, __float_as_int(dinv[d] * dinv[s]));
    }
}

// x0 -> packed bf16 x; h = alpha * x0 (exact f32).
__global__ void init_kernel(const float2* __restrict__ x0, unsigned int* __restrict__ xb,
                            float2* __restrict__ h, int n2) {
    int i = blockIdx.x * blockDim.x + threadIdx.x;
    if (i < n2) {
        float2 v = x0[i];
        xb[i] = pack_bf2(v.x, v.y);
        h[i] = make_float2(ALPHA * v.x, ALPHA * v.y);
    }
}

// One wave (64 lanes) per node; lane owns features [2*lane, 2*lane+1] (one packed dword).
// Edge records loaded 64-at-a-time coalesced, broadcast with shfl; gathers unrolled x16.
__global__ __launch_bounds__(256) void agg_kernel(
    const unsigned int* __restrict__ xb, unsigned int* __restrict__ yb,
    float2* __restrict__ h2, const float* __restrict__ selfw,
    const int* __restrict__ row_start, const int2* __restrict__ csr) {
    int wid = threadIdx.x >> 6;
    int lane = threadIdx.x & 63;
    int node = blockIdx.x * 4 + wid;
    if (node >= N_NODES) return;

    int r0 = row_start[node];
    int r1 = row_start[node + 1];
    int deg = r1 - r0;
    size_t o = (size_t)node * 64 + lane;

    unsigned int vw = xb[o];
    float sw = selfw[node];
    float accx = sw * bf_lo(vw), accy = sw * bf_hi(vw);

    for (int base = 0; base < deg; base += 64) {
        int cnt = deg - base;
        if (cnt > 64) cnt = 64;
        int idx = r0 + base + lane;
        if (idx >= r1) idx = r1 - 1;           // clamped lanes are never shfl-read
        int2 rec = csr[idx];                   // one coalesced dwordx2 per wave

        int j = 0;
        for (; j + 16 <= cnt; j += 16) {
            unsigned int g[16];
            float w[16];
            #pragma unroll
            for (int q = 0; q < 16; ++q) {
                int s = __shfl(rec.x, j + q);
                w[q] = __int_as_float(__shfl(rec.y, j + q));
                g[q] = xb[(size_t)s * 64 + lane];
            }
            #pragma unroll
            for (int q = 0; q < 16; ++q) {
                accx += w[q] * bf_lo(g[q]);
                accy += w[q] * bf_hi(g[q]);
            }
        }
        for (; j < cnt; ++j) {
            int s = __shfl(rec.x, j);
            float w = __int_as_float(__shfl(rec.y, j));
            unsigned int gw = xb[(size_t)s * 64 + lane];
            accx += w * bf_lo(gw);
            accy += w * bf_hi(gw);
        }
    }

    yb[o] = pack_bf2(accx, accy);              // bf16 state for next hop
    float2 hv = h2[o];                         // f32 accumulator fed pre-rounding
    hv.x += HCOEF * accx;
    hv.y += HCOEF * accy;
    h2[o] = hv;
}

// out[r][c] = sum_k h[r][k]*W[c][k] + bias[c]. h and out are DIFFERENT buffers.
// Block: 64 rows x 64 cols, 256 threads, 4x4 acc/thread. k-major LDS tiles.
__global__ __launch_bounds__(256) void gemm_kernel(
    const float* __restrict__ h, const float* __restrict__ w,
    const float* __restrict__ bias, float* __restrict__ out) {
    __shared__ float sAT[128][64];   // [k][row]
    __shared__ float sBT[128][64];   // [k][col]
    int tid = threadIdx.x;
    int row0 = blockIdx.x * 64;
    int col0 = blockIdx.y * 64;

    for (int idx = tid; idx < 64 * 32; idx += 256) {
        int r = idx & 63, kq = idx >> 6;
        float4 v;
        if (row0 + r < N_NODES)
            v = *(const float4*)&h[(size_t)(row0 + r) * D + kq * 4];
        else
            v = make_float4(0.f, 0.f, 0.f, 0.f);
        sAT[kq * 4 + 0][r] = v.x;
        sAT[kq * 4 + 1][r] = v.y;
        sAT[kq * 4 + 2][r] = v.z;
        sAT[kq * 4 + 3][r] = v.w;
    }
    for (int idx = tid; idx < 64 * 32; idx += 256) {
        int c = idx & 63, kq = idx >> 6;
        float4 v = *(const float4*)&w[(size_t)(col0 + c) * D + kq * 4];
        sBT[kq * 4 + 0][c] = v.x;
        sBT[kq * 4 + 1][c] = v.y;
        sBT[kq * 4 + 2][c] = v.z;
        sBT[kq * 4 + 3][c] = v.w;
    }
    __syncthreads();

    int cg = tid & 15;    // cols cg*4..+4
    int rg = tid >> 4;    // rows rg*4..+4
    float acc[4][4] = {};
    #pragma unroll 2
    for (int k = 0; k < 128; ++k) {
        float4 a = *(const float4*)&sAT[k][rg * 4];
        float4 b = *(const float4*)&sBT[k][cg * 4];
        acc[0][0] += a.x * b.x; acc[0][1] += a.x * b.y; acc[0][2] += a.x * b.z; acc[0][3] += a.x * b.w;
        acc[1][0] += a.y * b.x; acc[1][1] += a.y * b.y; acc[1][2] += a.y * b.z; acc[1][3] += a.y * b.w;
        acc[2][0] += a.z * b.x; acc[2][1] += a.z * b.y; acc[2][2] += a.z * b.z; acc[2][3] += a.z * b.w;
        acc[3][0] += a.w * b.x; acc[3][1] += a.w * b.y; acc[3][2] += a.w * b.z; acc[3][3] += a.w * b.w;
    }

    float4 bv = *(const float4*)&bias[col0 + cg * 4];
    #pragma unroll
    for (int i = 0; i < 4; ++i) {
        int r = row0 + rg * 4 + i;
        if (r < N_NODES) {
            float4 ov = make_float4(acc[i][0] + bv.x, acc[i][1] + bv.y,
                                    acc[i][2] + bv.z, acc[i][3] + bv.w);
            *(float4*)&out[(size_t)r * D + col0 + cg * 4] = ov;
        }
    }
}

extern "C" void kernel_launch(void* const* d_in, const int* in_sizes, int n_in,
                              void* d_out, int out_size, void* d_ws, size_t ws_size,
                              hipStream_t stream) {
    const float* node_emb = (const float*)d_in[0];
    const int*   edge     = (const int*)d_in[1];   // [2,E]: row 0 = src, row 1 = dst
    const float* weight   = (const float*)d_in[2]; // [D_OUT, D_IN] row-major
    const float* bias     = (const float*)d_in[3];
    float* out = (float*)d_out;

    char* ws = (char*)d_ws;
    float*        hbuf = (float*)ws;        ws += (size_t)N_NODES * D * sizeof(float);
    unsigned int* xb0  = (unsigned int*)ws; ws += (size_t)N_NODES * 64 * sizeof(unsigned int);
    unsigned int* xb1  = (unsigned int*)ws; ws += (size_t)N_NODES * 64 * sizeof(unsigned int);
    int2*  csr      = (int2*)ws;  ws += (size_t)N_EDGES * sizeof(int2);
    int*   rank     = (int*)ws;   ws += (size_t)N_EDGES * sizeof(int);
    int*   deg      = (int*)ws;   ws += (size_t)N_NODES * sizeof(int);
    int*   row_start= (int*)ws;   ws += (size_t)(N_NODES + 1) * sizeof(int);
    float* dinv     = (float*)ws; ws += (size_t)N_NODES * sizeof(float);
    float* selfw    = (float*)ws; ws += (size_t)N_NODES * sizeof(float);

    const int* srcp = edge;
    const int* dstp = edge + N_EDGES;

    hipMemsetAsync(deg, 0, N_NODES * sizeof(int), stream);

    deg_kernel<<<(N_EDGES + 255) / 256, 256, 0, stream>>>(dstp, deg, rank, N_EDGES);
    dinv_kernel<<<(N_NODES + 255) / 256, 256, 0, stream>>>(deg, dinv, selfw, N_NODES);
    scan_kernel<<<1, 1024, 0, stream>>>(deg, row_start, N_NODES);
    scatter_kernel<<<(N_EDGES + 255) / 256, 256, 0, stream>>>(srcp, dstp, rank, row_start,
                                                              csr, dinv, N_EDGES);

    int n2 = N_NODES * D / 2;
    init_kernel<<<(n2 + 255) / 256, 256, 0, stream>>>((const float2*)node_emb, xb0,
                                                      (float2*)hbuf, n2);

    unsigned int* cur = xb0;
    unsigned int* nxt = xb1;
    for (int k = 0; k < K_HOPS; ++k) {
        agg_kernel<<<(N_NODES + 3) / 4, 256, 0, stream>>>(cur, nxt, (float2*)hbuf,
                                                          selfw, row_start, csr);
        unsigned int* tmp = cur; cur = nxt; nxt = tmp;
    }

    // Out-of-place GEMM: reads hbuf (f32), writes d_out.
    dim3 ggrid((N_NODES + 63) / 64, 2);
    gemm_kernel<<<ggrid, 256, 0, stream>>>(hbuf, weight, bias, out);
}

// Round 7
// 1103.736 us; speedup vs baseline: 3.0388x; 1.1254x over previous
//
#include <hip/hip_runtime.h>

// SSGC: h = alpha*x0 + (1-alpha)/K * sum_{k=1..K} (D^-1/2 A_hat D^-1/2)^k x0 ; out = h W^T + b
// N=50000, E=1.6M, D=128, K=16, alpha=0.05.
// R7: R6 minus the 4x-ILP deg kernel (reverted to R5's simple form after an untraced
//     SIGABRT). Keeps: bf16 feature rows, stepped gather tails (16/8/4/scalar),
//     h RMW every 2 hops (pairs x_k via the rounded self-row), packed 8B edge records.

#define N_NODES 50000
#define N_EDGES 1600000
#define D 128
#define K_HOPS 16
#define ALPHA 0.05f
#define HCOEF ((1.0f - ALPHA) / (float)K_HOPS)

__device__ __forceinline__ unsigned int f2bf(float f) {
    unsigned int u = __float_as_uint(f);
    return (u + 0x7FFFu + ((u >> 16) & 1u)) >> 16;   // RNE
}
__device__ __forceinline__ unsigned int pack_bf2(float x, float y) {
    return f2bf(x) | (f2bf(y) << 16);
}
__device__ __forceinline__ float bf_lo(unsigned int w) { return __uint_as_float(w << 16); }
__device__ __forceinline__ float bf_hi(unsigned int w) { return __uint_as_float(w & 0xFFFF0000u); }

// Count in-degree and assign each edge its within-destination rank (coalesced write).
__global__ void deg_kernel(const int* __restrict__ dst, int* __restrict__ deg,
                           int* __restrict__ rank, int e) {
    int i = blockIdx.x * blockDim.x + threadIdx.x;
    if (i < e) rank[i] = atomicAdd(&deg[dst[i]], 1);
}

// dinv = 1/sqrt(deg+1); selfw = dinv^2 (self-loop weight)
__global__ void dinv_kernel(const int* __restrict__ deg, float* __restrict__ dinv,
                            float* __restrict__ selfw, int n) {
    int i = blockIdx.x * blockDim.x + threadIdx.x;
    if (i < n) {
        float di = rsqrtf((float)(deg[i] + 1));
        dinv[i] = di;
        selfw[i] = di * di;
    }
}

// Exclusive scan of deg -> row_start. Single block, 1024 threads, shfl wave scans.
__global__ void scan_kernel(const int* __restrict__ deg, int* __restrict__ row_start, int n) {
    __shared__ int wsum[16];
    __shared__ int tot_s;
    __shared__ int carry_s;
    int tid = threadIdx.x, lane = tid & 63, wid = tid >> 6;
    if (tid == 0) carry_s = 0;
    __syncthreads();
    for (int base = 0; base < n; base += 1024) {
        int i = base + tid;
        int v = (i < n) ? deg[i] : 0;
        int s = v;
        #pragma unroll
        for (int off = 1; off < 64; off <<= 1) {
            int t = __shfl_up(s, off, 64);
            if (lane >= off) s += t;
        }
        if (lane == 63) wsum[wid] = s;
        __syncthreads();                       // (A) wsum ready
        if (tid == 0) {
            int run = 0;
            #pragma unroll
            for (int w = 0; w < 16; ++w) { int t = wsum[w]; wsum[w] = run; run += t; }
            tot_s = run;
        }
        __syncthreads();                       // (B) offsets ready, carry stable
        if (i < n) row_start[i] = carry_s + wsum[wid] + (s - v);
        __syncthreads();                       // (C) all reads of carry_s done
        if (tid == 0) carry_s += tot_s;
    }
    __syncthreads();
    if (tid == 0) row_start[n] = carry_s;
}

// One 8B scattered store per edge: record = (src, bitcast(norm weight)).
__global__ void scatter_kernel(const int* __restrict__ src, const int* __restrict__ dst,
                               const int* __restrict__ rank,
                               const int* __restrict__ row_start, int2* __restrict__ csr,
                               const float* __restrict__ dinv, int e) {
    int i = blockIdx.x * blockDim.x + threadIdx.x;
    if (i < e) {
        int d = dst[i];
        int s = src[i];
        int pos = row_start[d] + rank[i];
        csr[pos] = make_int2(s, __float_as_int(dinv[d] * dinv[s]));
    }
}

// x0 -> packed bf16 x; h = alpha * x0 (exact f32).
__global__ void init_kernel(const float2* __restrict__ x0, unsigned int* __restrict__ xb,
                            float2* __restrict__ h, int n2) {
    int i = blockIdx.x * blockDim.x + threadIdx.x;
    if (i < n2) {
        float2 v = x0[i];
        xb[i] = pack_bf2(v.x, v.y);
        h[i] = make_float2(ALPHA * v.x, ALPHA * v.y);
    }
}

#define GATHER_BLOCK(W)                                                         \
    {                                                                           \
        unsigned int g[W];                                                      \
        float wv[W];                                                            \
        _Pragma("unroll") for (int q = 0; q < W; ++q) {                         \
            int s = __shfl(rec.x, j + q);                                       \
            wv[q] = __int_as_float(__shfl(rec.y, j + q));                       \
            g[q] = xb[(size_t)s * 64 + lane];                                   \
        }                                                                       \
        _Pragma("unroll") for (int q = 0; q < W; ++q) {                         \
            accx += wv[q] * bf_lo(g[q]);                                        \
            accy += wv[q] * bf_hi(g[q]);                                        \
        }                                                                       \
        j += W;                                                                 \
    }

// One wave (64 lanes) per node; lane owns features [2*lane, 2*lane+1] (one packed dword).
// Edge records loaded 64-at-a-time coalesced, broadcast with shfl; stepped unroll 16/8/4.
// update_h: h += c*(x_k + x_{k+1}) using the rounded self-row (x_k) + fresh acc (x_{k+1}).
__global__ __launch_bounds__(256) void agg_kernel(
    const unsigned int* __restrict__ xb, unsigned int* __restrict__ yb,
    float2* __restrict__ h2, const float* __restrict__ selfw,
    const int* __restrict__ row_start, const int2* __restrict__ csr, int update_h) {
    int wid = threadIdx.x >> 6;
    int lane = threadIdx.x & 63;
    int node = blockIdx.x * 4 + wid;
    if (node >= N_NODES) return;

    int r0 = row_start[node];
    int r1 = row_start[node + 1];
    int deg = r1 - r0;
    size_t o = (size_t)node * 64 + lane;

    unsigned int vw = xb[o];
    float sw = selfw[node];
    float accx = sw * bf_lo(vw), accy = sw * bf_hi(vw);

    for (int base = 0; base < deg; base += 64) {
        int cnt = deg - base;
        if (cnt > 64) cnt = 64;
        int idx = r0 + base + lane;
        if (idx >= r1) idx = r1 - 1;           // clamped lanes are never shfl-read
        int2 rec = csr[idx];                   // one coalesced dwordx2 per wave

        int j = 0;
        while (j + 16 <= cnt) GATHER_BLOCK(16);
        if (j + 8 <= cnt) GATHER_BLOCK(8);
        if (j + 4 <= cnt) GATHER_BLOCK(4);
        for (; j < cnt; ++j) {
            int s = __shfl(rec.x, j);
            float w = __int_as_float(__shfl(rec.y, j));
            unsigned int gw = xb[(size_t)s * 64 + lane];
            accx += w * bf_lo(gw);
            accy += w * bf_hi(gw);
        }
    }

    yb[o] = pack_bf2(accx, accy);              // bf16 state for next hop
    if (update_h) {
        float2 hv = h2[o];
        hv.x += HCOEF * (bf_lo(vw) + accx);    // x_k (rounded) + x_{k+1} (pre-round)
        hv.y += HCOEF * (bf_hi(vw) + accy);
        h2[o] = hv;
    }
}

// out[r][c] = sum_k h[r][k]*W[c][k] + bias[c]. h and out are DIFFERENT buffers.
// Block: 64 rows x 64 cols, 256 threads, 4x4 acc/thread. k-major LDS tiles.
__global__ __launch_bounds__(256) void gemm_kernel(
    const float* __restrict__ h, const float* __restrict__ w,
    const float* __restrict__ bias, float* __restrict__ out) {
    __shared__ float sAT[128][64];   // [k][row]
    __shared__ float sBT[128][64];   // [k][col]
    int tid = threadIdx.x;
    int row0 = blockIdx.x * 64;
    int col0 = blockIdx.y * 64;

    for (int idx = tid; idx < 64 * 32; idx += 256) {
        int r = idx & 63, kq = idx >> 6;
        float4 v;
        if (row0 + r < N_NODES)
            v = *(const float4*)&h[(size_t)(row0 + r) * D + kq * 4];
        else
            v = make_float4(0.f, 0.f, 0.f, 0.f);
        sAT[kq * 4 + 0][r] = v.x;
        sAT[kq * 4 + 1][r] = v.y;
        sAT[kq * 4 + 2][r] = v.z;
        sAT[kq * 4 + 3][r] = v.w;
    }
    for (int idx = tid; idx < 64 * 32; idx += 256) {
        int c = idx & 63, kq = idx >> 6;
        float4 v = *(const float4*)&w[(size_t)(col0 + c) * D + kq * 4];
        sBT[kq * 4 + 0][c] = v.x;
        sBT[kq * 4 + 1][c] = v.y;
        sBT[kq * 4 + 2][c] = v.z;
        sBT[kq * 4 + 3][c] = v.w;
    }
    __syncthreads();

    int cg = tid & 15;    // cols cg*4..+4
    int rg = tid >> 4;    // rows rg*4..+4
    float acc[4][4] = {};
    #pragma unroll 2
    for (int k = 0; k < 128; ++k) {
        float4 a = *(const float4*)&sAT[k][rg * 4];
        float4 b = *(const float4*)&sBT[k][cg * 4];
        acc[0][0] += a.x * b.x; acc[0][1] += a.x * b.y; acc[0][2] += a.x * b.z; acc[0][3] += a.x * b.w;
        acc[1][0] += a.y * b.x; acc[1][1] += a.y * b.y; acc[1][2] += a.y * b.z; acc[1][3] += a.y * b.w;
        acc[2][0] += a.z * b.x; acc[2][1] += a.z * b.y; acc[2][2] += a.z * b.z; acc[2][3] += a.z * b.w;
        acc[3][0] += a.w * b.x; acc[3][1] += a.w * b.y; acc[3][2] += a.w * b.z; acc[3][3] += a.w * b.w;
    }

    float4 bv = *(const float4*)&bias[col0 + cg * 4];
    #pragma unroll
    for (int i = 0; i < 4; ++i) {
        int r = row0 + rg * 4 + i;
        if (r < N_NODES) {
            float4 ov = make_float4(acc[i][0] + bv.x, acc[i][1] + bv.y,
                                    acc[i][2] + bv.z, acc[i][3] + bv.w);
            *(float4*)&out[(size_t)r * D + col0 + cg * 4] = ov;
        }
    }
}

extern "C" void kernel_launch(void* const* d_in, const int* in_sizes, int n_in,
                              void* d_out, int out_size, void* d_ws, size_t ws_size,
                              hipStream_t stream) {
    const float* node_emb = (const float*)d_in[0];
    const int*   edge     = (const int*)d_in[1];   // [2,E]: row 0 = src, row 1 = dst
    const float* weight   = (const float*)d_in[2]; // [D_OUT, D_IN] row-major
    const float* bias     = (const float*)d_in[3];
    float* out = (float*)d_out;

    char* ws = (char*)d_ws;
    float*        hbuf = (float*)ws;        ws += (size_t)N_NODES * D * sizeof(float);
    unsigned int* xb0  = (unsigned int*)ws; ws += (size_t)N_NODES * 64 * sizeof(unsigned int);
    unsigned int* xb1  = (unsigned int*)ws; ws += (size_t)N_NODES * 64 * sizeof(unsigned int);
    int2*  csr      = (int2*)ws;  ws += (size_t)N_EDGES * sizeof(int2);
    int*   rank     = (int*)ws;   ws += (size_t)N_EDGES * sizeof(int);
    int*   deg      = (int*)ws;   ws += (size_t)N_NODES * sizeof(int);
    int*   row_start= (int*)ws;   ws += (size_t)(N_NODES + 1) * sizeof(int);
    float* dinv     = (float*)ws; ws += (size_t)N_NODES * sizeof(float);
    float* selfw    = (float*)ws; ws += (size_t)N_NODES * sizeof(float);

    const int* srcp = edge;
    const int* dstp = edge + N_EDGES;

    hipMemsetAsync(deg, 0, N_NODES * sizeof(int), stream);

    deg_kernel<<<(N_EDGES + 255) / 256, 256, 0, stream>>>(dstp, deg, rank, N_EDGES);
    dinv_kernel<<<(N_NODES + 255) / 256, 256, 0, stream>>>(deg, dinv, selfw, N_NODES);
    scan_kernel<<<1, 1024, 0, stream>>>(deg, row_start, N_NODES);
    scatter_kernel<<<(N_EDGES + 255) / 256, 256, 0, stream>>>(srcp, dstp, rank, row_start,
                                                              csr, dinv, N_EDGES);

    int n2 = N_NODES * D / 2;
    init_kernel<<<(n2 + 255) / 256, 256, 0, stream>>>((const float2*)node_emb, xb0,
                                                      (float2*)hbuf, n2);

    unsigned int* cur = xb0;
    unsigned int* nxt = xb1;
    for (int k = 0; k < K_HOPS; ++k) {
        agg_kernel<<<(N_NODES + 3) / 4, 256, 0, stream>>>(cur, nxt, (float2*)hbuf,
                                                          selfw, row_start, csr, k & 1);
        unsigned int* tmp = cur; cur = nxt; nxt = tmp;
    }

    // Out-of-place GEMM: reads hbuf (f32), writes d_out.
    dim3 ggrid((N_NODES + 63) / 64, 2);
    gemm_kernel<<<ggrid, 256, 0, stream>>>(hbuf, weight, bias, out);
}